// Round 19
// baseline (216.598 us; speedup 1.0000x reference)
//
#include <hip/hip_runtime.h>

#define DD 128

typedef __attribute__((ext_vector_type(8))) short bf16x8;
typedef __attribute__((ext_vector_type(4))) float f32x4;

// ---- bf16 helpers (RNE) ----------------------------------------------------
__device__ inline unsigned short f2bf(float f) {
    unsigned int u = __float_as_uint(f);
    u += 0x7FFFu + ((u >> 16) & 1u);
    return (unsigned short)(u >> 16);
}
__device__ inline float bf2f(unsigned short s) {
    return __uint_as_float(((unsigned int)s) << 16);
}

template <typename T> __device__ inline T cvt(float f);
template <> __device__ inline float cvt<float>(float f) { return f; }
template <> __device__ inline unsigned short cvt<unsigned short>(float f) { return f2bf(f); }

template <typename T> __device__ inline float2 ld2(const T* p);
template <> __device__ inline float2 ld2<float>(const float* p) {
    return *reinterpret_cast<const float2*>(p);
}
template <> __device__ inline float2 ld2<unsigned short>(const unsigned short* p) {
    const ushort2 u = *reinterpret_cast<const ushort2*>(p);
    return make_float2(bf2f(u.x), bf2f(u.y));
}

// ---------------------------------------------------------------------------
// Plain-bf16 MFMA pipeline (round-18 structure, best measured 214.0us).
// Round 19: same LDS-staged coalesced epilogue applied to out_mfma (its
// D-fragment stores were 64B-segment strided fp32 writes).
// ---------------------------------------------------------------------------

// One-shot: weights -> bf16 B-fragment layout; also zeroes deg/cnt2/done.
__global__ __launch_bounds__(256) void split_w_kernel(
    const float* __restrict__ W0, const float* __restrict__ W1,
    const float* __restrict__ W2, const float* __restrict__ W3,
    const float* __restrict__ W4,
    unsigned short* __restrict__ whi,
    int* __restrict__ deg, int* __restrict__ cnt2, int* __restrict__ done,
    int N)
{
    const int gid = blockIdx.x * 256 + threadIdx.x;
    if (gid < N) { deg[gid] = 0; cnt2[gid] = 0; }
    if (gid == 0) *done = 0;

    const int idx = gid;                              // 5 * 2048 frags
    if (idx >= 5 * 2048) return;
    const int mat  = idx >> 11;
    const int rem  = idx & 2047;
    const int ks   = rem >> 9;
    const int nt   = (rem >> 6) & 7;
    const int lane = rem & 63;
    const int lr = lane & 15, lg = lane >> 4;
    const float* __restrict__ W = mat == 0 ? W0 : mat == 1 ? W1 : mat == 2 ? W2
                                 : mat == 3 ? W3 : W4;
    const int n = nt * 16 + lr;
    bf16x8 h8;
#pragma unroll
    for (int r = 0; r < 8; ++r) {
        const int k = ks * 32 + lg * 8 + r;
        h8[r] = (short)f2bf(W[k * DD + n]);
    }
    *reinterpret_cast<bf16x8*>(&whi[(long)idx * 8]) = h8;
}

// Stage 64 rows x 128 cols of fp32 A as bf16 fragments in LDS (512 threads).
template <bool XFORM>
__device__ inline void stage_rows512(const float* __restrict__ src,
                                     const float* __restrict__ addv,
                                     int row0, int N, int t,
                                     unsigned short* __restrict__ ldsA)
{
    const int m  = t >> 3;            // 0..63 local row
    const int gr = row0 + m;
#pragma unroll
    for (int j = 0; j < 2; ++j) {
        const int o = (t & 7) + j * 8;   // k-octet 0..15
        float v[8];
        if (gr < N) {
            const float4 a = *reinterpret_cast<const float4*>(&src[(long)gr * DD + o * 8]);
            const float4 b = *reinterpret_cast<const float4*>(&src[(long)gr * DD + o * 8 + 4]);
            v[0] = a.x; v[1] = a.y; v[2] = a.z; v[3] = a.w;
            v[4] = b.x; v[5] = b.y; v[6] = b.z; v[7] = b.w;
        } else {
#pragma unroll
            for (int e = 0; e < 8; ++e) v[e] = 0.f;
        }
        if (XFORM) {   // leaky_relu(src + addv) fused into staging
#pragma unroll
            for (int e = 0; e < 8; ++e) {
                const float s = v[e] + addv[o * 8 + e];
                v[e] = s >= 0.f ? s : 0.01f * s;
            }
        }
        bf16x8 h8;
#pragma unroll
        for (int e = 0; e < 8; ++e) h8[e] = (short)f2bf(v[e]);
        const int rt   = m >> 4;
        const int ks   = o >> 2;
        const int lane = (m & 15) + (o & 3) * 16;
        const int base = ((rt * 4 + ks) * 64 + lane) * 8;
        *reinterpret_cast<bf16x8*>(&ldsA[base]) = h8;
    }
}

// ---------------------------------------------------------------------------
// Kernel (MFMA, 512 thr / 8 waves): fused node projections + histogram tail.
// Epilogue staged in LDS for coalesced writes (round-18 validated).
// ---------------------------------------------------------------------------
__global__ __launch_bounds__(512) void proj_mfma_kernel(
    const float* __restrict__ x,
    const unsigned short* __restrict__ whi,
    const float* __restrict__ bk, const float* __restrict__ bq,
    const float* __restrict__ bv,
    unsigned short* __restrict__ kbuf, unsigned short* __restrict__ qvpk,
    float* __restrict__ agg,
    const int* __restrict__ ei, int* __restrict__ deg,
    int projBlocks, int E, int N)
{
    __shared__ unsigned short smem[16384];        // 32 KB multi-purpose
    const int t = threadIdx.x;

    if (blockIdx.x >= projBlocks) {               // histogram role
        const int e = (blockIdx.x - projBlocks) * 512 + t;
        if (e < E) atomicAdd(&deg[ei[E + e]], 1);
        return;
    }

    const int row0 = blockIdx.x * 64;
    stage_rows512<false>(x, nullptr, row0, N, t, smem);   // uses first 16KB
    __syncthreads();

    const int wv   = t >> 6;
    const int mat  = wv >> 1;
    const int cc   = wv & 1;
    const int lane = t & 63;
    const int lr = lane & 15;
    const int lg = lane >> 4;

    f32x4 acc[4][4];
#pragma unroll
    for (int rt = 0; rt < 4; ++rt)
#pragma unroll
        for (int ct = 0; ct < 4; ++ct) acc[rt][ct] = (f32x4){0.f, 0.f, 0.f, 0.f};

#pragma unroll
    for (int ks = 0; ks < 4; ++ks) {
        bf16x8 A[4];
#pragma unroll
        for (int rt = 0; rt < 4; ++rt)
            A[rt] = *reinterpret_cast<const bf16x8*>(&smem[((rt * 4 + ks) * 64 + lane) * 8]);
#pragma unroll
        for (int ct = 0; ct < 4; ++ct) {
            const long fb = ((long)((mat * 4 + ks) * 8 + (cc * 4 + ct)) * 64 + lane) * 8;
            const bf16x8 B = *reinterpret_cast<const bf16x8*>(&whi[fb]);
#pragma unroll
            for (int rt = 0; rt < 4; ++rt)
                acc[rt][ct] = __builtin_amdgcn_mfma_f32_16x16x32_bf16(A[rt], B, acc[rt][ct], 0, 0, 0);
        }
    }
    __syncthreads();   // ldsA reads complete; smem free for staging

    // ---- Phase 1: Q/V -> smem[64][256] bf16, then coalesced copy ----
    if (mat == 1 || mat == 2) {
        const float* bias2 = (mat == 1) ? bq : bv;
        const int sub = mat - 1;
#pragma unroll
        for (int ct = 0; ct < 4; ++ct) {
            const int n_l = cc * 64 + ct * 16 + lr;
            const float bb = bias2[n_l];
#pragma unroll
            for (int rt = 0; rt < 4; ++rt)
#pragma unroll
                for (int r = 0; r < 4; ++r) {
                    const int m = rt * 16 + lg * 4 + r;
                    smem[m * 256 + 2 * n_l + sub] = f2bf(acc[rt][ct][r] + bb);
                }
        }
    }
    __syncthreads();
    {
        const int row = t >> 3;
        const int c0  = (t & 7) * 32;
        if (row0 + row < N) {
            const bf16x8* sp = reinterpret_cast<const bf16x8*>(&smem[row * 256 + c0]);
            bf16x8* dp = reinterpret_cast<bf16x8*>(&qvpk[(long)(row0 + row) * 256 + c0]);
#pragma unroll
            for (int i = 0; i < 4; ++i) dp[i] = sp[i];
        }
    }
    __syncthreads();

    // ---- Phase 2: K -> smem[64][128] bf16, then coalesced copy ----
    if (mat == 0) {
#pragma unroll
        for (int ct = 0; ct < 4; ++ct) {
            const int n_l = cc * 64 + ct * 16 + lr;
            const float bb = bk[n_l];
#pragma unroll
            for (int rt = 0; rt < 4; ++rt)
#pragma unroll
                for (int r = 0; r < 4; ++r) {
                    const int m = rt * 16 + lg * 4 + r;
                    smem[m * 128 + n_l] = f2bf(acc[rt][ct][r] + bb);
                }
        }
    }
    __syncthreads();
    {
        const int row = t >> 3;
        const int c0  = (t & 7) * 16;
        if (row0 + row < N) {
            const bf16x8* sp = reinterpret_cast<const bf16x8*>(&smem[row * 128 + c0]);
            bf16x8* dp = reinterpret_cast<bf16x8*>(&kbuf[(long)(row0 + row) * 128 + c0]);
            dp[0] = sp[0]; dp[1] = sp[1];
        }
    }
    __syncthreads();

    // ---- Phase 3: Skip/agg -> smem[64][128] fp32 (32KB), coalesced copy ----
    float* smf = reinterpret_cast<float*>(smem);
    if (mat == 3) {
#pragma unroll
        for (int ct = 0; ct < 4; ++ct) {
            const int n_l = cc * 64 + ct * 16 + lr;
#pragma unroll
            for (int rt = 0; rt < 4; ++rt)
#pragma unroll
                for (int r = 0; r < 4; ++r) {
                    const int m = rt * 16 + lg * 4 + r;
                    smf[m * 128 + n_l] = acc[rt][ct][r];
                }
        }
    }
    __syncthreads();
    {
        const int row = t >> 3;
        const int c0  = (t & 7) * 16;
        if (row0 + row < N) {
            const float4* sp = reinterpret_cast<const float4*>(&smf[row * 128 + c0]);
            float4* dp = reinterpret_cast<float4*>(&agg[(long)(row0 + row) * 128 + c0]);
#pragma unroll
            for (int i = 0; i < 4; ++i) dp[i] = sp[i];
        }
    }
}

// ---------------------------------------------------------------------------
// Fused scan: per-chunk scan + chunk totals; last block scans bsum in place.
// ---------------------------------------------------------------------------
__global__ __launch_bounds__(1024) void scanAB_kernel(
    const int* __restrict__ deg, int* __restrict__ off,
    int* __restrict__ bsum, int* __restrict__ done, int N, int nb)
{
    __shared__ int sm[1024];
    __shared__ int amLast;
    const int t = threadIdx.x;
    const int i = blockIdx.x * 1024 + t;
    const int v = (i < N) ? deg[i] : 0;
    int x = v;
    sm[t] = x;
    __syncthreads();
#pragma unroll
    for (int ofs = 1; ofs < 1024; ofs <<= 1) {
        const int y = (t >= ofs) ? sm[t - ofs] : 0;
        __syncthreads();
        x += y;
        sm[t] = x;
        __syncthreads();
    }
    if (i < N) off[i] = x - v;
    if (t == 1023) { bsum[blockIdx.x] = x; __threadfence(); }
    __syncthreads();
    if (t == 0) amLast = (atomicAdd(done, 1) == (int)gridDim.x - 1) ? 1 : 0;
    __syncthreads();
    if (!amLast) return;

    const int vb = (t < nb) ? atomicAdd(&bsum[t], 0) : 0;
    int xb = vb;
    sm[t] = xb;
    __syncthreads();
#pragma unroll
    for (int ofs = 1; ofs < 1024; ofs <<= 1) {
        const int y = (t >= ofs) ? sm[t - ofs] : 0;
        __syncthreads();
        xb += y;
        sm[t] = xb;
        __syncthreads();
    }
    if (t < nb) bsum[t] = xb - vb;
}

// scatter: pos = off[d] + bsum[chunk] + cnt2[d]++
__global__ __launch_bounds__(256) void scatter2_kernel(
    const int* __restrict__ ei,
    const int* __restrict__ off, const int* __restrict__ bsum,
    int* __restrict__ cnt2, int* __restrict__ ssrc, int E)
{
    const int e = blockIdx.x * 256 + threadIdx.x;
    if (e >= E) return;
    const int s = ei[e];
    const int d = ei[E + e];
    const int pos = off[d] + bsum[d >> 10] + atomicAdd(&cnt2[d], 1);
    ssrc[pos] = s;
}

// ---------------------------------------------------------------------------
// Kernel (MFMA, 512 thr / 8 waves): out = leaky(agg + b_conv) @ Wlin + blin.
// agg aliases out. Round 19: epilogue staged via LDS (32KB) for coalesced
// float4 stores (D-fragment direct stores were 64B segments @512B stride).
// ---------------------------------------------------------------------------
__global__ __launch_bounds__(512) void out_mfma_kernel(
    const float* agg, const float* __restrict__ bconv,
    const unsigned short* __restrict__ whi,
    const float* __restrict__ blin,
    float* out, int N)
{
    __shared__ unsigned short smem[16384];        // 32 KB multi-purpose
    const int t = threadIdx.x;
    const int row0 = blockIdx.x * 64;

    stage_rows512<true>(agg, bconv, row0, N, t, smem);   // first 16KB
    __syncthreads();

    const int wv   = t >> 6;
    const int lane = t & 63;
    const int lr = lane & 15;
    const int lg = lane >> 4;

    f32x4 acc[4];
#pragma unroll
    for (int rt = 0; rt < 4; ++rt) acc[rt] = (f32x4){0.f, 0.f, 0.f, 0.f};

#pragma unroll
    for (int ks = 0; ks < 4; ++ks) {
        bf16x8 A[4];
#pragma unroll
        for (int rt = 0; rt < 4; ++rt)
            A[rt] = *reinterpret_cast<const bf16x8*>(&smem[((rt * 4 + ks) * 64 + lane) * 8]);
        const long fb = ((long)((16 + ks) * 8 + wv) * 64 + lane) * 8;
        const bf16x8 B = *reinterpret_cast<const bf16x8*>(&whi[fb]);
#pragma unroll
        for (int rt = 0; rt < 4; ++rt)
            acc[rt] = __builtin_amdgcn_mfma_f32_16x16x32_bf16(A[rt], B, acc[rt], 0, 0, 0);
    }
    __syncthreads();   // fragment reads done; smem free

    // stage results row-major fp32 in smem[64][128] then coalesced copy
    float* smf = reinterpret_cast<float*>(smem);
    {
        const int n = wv * 16 + lr;
        const float bb = blin[n];
#pragma unroll
        for (int rt = 0; rt < 4; ++rt)
#pragma unroll
            for (int r = 0; r < 4; ++r) {
                const int m = rt * 16 + lg * 4 + r;
                smf[m * 128 + n] = acc[rt][r] + bb;
            }
    }
    __syncthreads();
    {
        const int row = t >> 3;
        const int c0  = (t & 7) * 16;
        if (row0 + row < N) {
            const float4* sp = reinterpret_cast<const float4*>(&smf[row * 128 + c0]);
            float4* dp = reinterpret_cast<float4*>(&out[(long)(row0 + row) * 128 + c0]);
#pragma unroll
            for (int i = 0; i < 4; ++i) dp[i] = sp[i];
        }
    }
}

// ---------------------------------------------------------------------------
// Gather (packed): one wave per dst node; lane owns channels (2L, 2L+1).
// 8-edge unroll (round-11 proven). kbuf bf16 (round-17 validated).
// ---------------------------------------------------------------------------
__global__ __launch_bounds__(256) void gather_packed_kernel(
    const int* __restrict__ off, const int* __restrict__ bsum,
    const int* __restrict__ deg, const int* __restrict__ ssrc,
    const unsigned short* __restrict__ kbuf, const unsigned short* __restrict__ qvpk,
    float* __restrict__ agg, int N)
{
    const int n = blockIdx.x * 4 + (threadIdx.x >> 6);
    if (n >= N) return;
    const int lane = threadIdx.x & 63;

    const int dg = deg[n];
    if (dg == 0) return;
    const int s0 = off[n] + bsum[n >> 10];
    const int s1 = s0 + dg;

    const ushort2 ku = *reinterpret_cast<const ushort2*>(&kbuf[(long)n * 128 + lane * 2]);
    const float k0 = bf2f(ku.x), k1 = bf2f(ku.y);
    float a0 = 0.f, a1 = 0.f, b0 = 0.f, b1 = 0.f;

    int e = s0;
    for (; e + 8 <= s1; e += 8) {
        int s[8];
#pragma unroll
        for (int j = 0; j < 8; ++j) s[j] = ssrc[e + j];
        ushort4 u[8];
#pragma unroll
        for (int j = 0; j < 8; ++j)
            u[j] = *reinterpret_cast<const ushort4*>(&qvpk[(long)s[j] * 256 + lane * 4]);
#pragma unroll
        for (int j = 0; j < 8; ++j) {
            const float q0 = bf2f(u[j].x), v0 = bf2f(u[j].y);
            const float q1 = bf2f(u[j].z), v1 = bf2f(u[j].w);
            if (j & 1) {
                b0 = fmaf(fmaxf(k0 + q0, 0.f), v0, b0);
                b1 = fmaf(fmaxf(k1 + q1, 0.f), v1, b1);
            } else {
                a0 = fmaf(fmaxf(k0 + q0, 0.f), v0, a0);
                a1 = fmaf(fmaxf(k1 + q1, 0.f), v1, a1);
            }
        }
    }
    for (; e < s1; ++e) {
        const int s = ssrc[e];
        const ushort4 u = *reinterpret_cast<const ushort4*>(&qvpk[(long)s * 256 + lane * 4]);
        a0 = fmaf(fmaxf(k0 + bf2f(u.x), 0.f), bf2f(u.y), a0);
        a1 = fmaf(fmaxf(k1 + bf2f(u.z), 0.f), bf2f(u.w), a1);
    }

    float2* ap = reinterpret_cast<float2*>(&agg[(long)n * 128 + lane * 2]);
    const float2 old = *ap;
    *ap = make_float2(old.x + a0 + b0, old.y + a1 + b1);
}

// ===========================================================================
// Fallback-path kernels (unchanged, proven round-5 structure)
// ===========================================================================
template <typename T>
__global__ __launch_bounds__(256) void proj_kernel(
    const float* __restrict__ x,
    const float* __restrict__ Wk, const float* __restrict__ bk,
    const float* __restrict__ Wq, const float* __restrict__ bq,
    const float* __restrict__ Wv, const float* __restrict__ bv,
    const float* __restrict__ Ws,
    T* __restrict__ kbuf, T* __restrict__ qvbuf, float* __restrict__ agg,
    int N)
{
    __shared__ float xt[32][DD];
    const int row0 = blockIdx.x * 32;
    const int t = threadIdx.x;

    for (int i = t; i < 32 * (DD / 4); i += 256) {
        const int r  = i >> 5;
        const int c4 = (i & 31) << 2;
        const int gr = row0 + r;
        float4 v = make_float4(0.f, 0.f, 0.f, 0.f);
        if (gr < N) v = *reinterpret_cast<const float4*>(&x[(long)gr * DD + c4]);
        *reinterpret_cast<float4*>(&xt[r][c4]) = v;
    }
    __syncthreads();

    const int c0 = t & 127;
    const int hi = t >> 7;
    const float* __restrict__ W0 = hi ? Wq : Wk;
    const float* __restrict__ W1 = hi ? Ws : Wv;
    const float b0 = hi ? bq[c0] : bk[c0];
    const float b1 = hi ? 0.f    : bv[c0];

    float acc0[32], acc1[32];
#pragma unroll
    for (int r = 0; r < 32; ++r) { acc0[r] = 0.f; acc1[r] = 0.f; }

    for (int k4 = 0; k4 < DD; k4 += 4) {
        const float w00 = W0[(k4 + 0) * DD + c0];
        const float w01 = W0[(k4 + 1) * DD + c0];
        const float w02 = W0[(k4 + 2) * DD + c0];
        const float w03 = W0[(k4 + 3) * DD + c0];
        const float w10 = W1[(k4 + 0) * DD + c0];
        const float w11 = W1[(k4 + 1) * DD + c0];
        const float w12 = W1[(k4 + 2) * DD + c0];
        const float w13 = W1[(k4 + 3) * DD + c0];
#pragma unroll
        for (int r = 0; r < 32; ++r) {
            const float4 xv = *reinterpret_cast<const float4*>(&xt[r][k4]);
            acc0[r] = fmaf(xv.x, w00, fmaf(xv.y, w01, fmaf(xv.z, w02, fmaf(xv.w, w03, acc0[r]))));
            acc1[r] = fmaf(xv.x, w10, fmaf(xv.y, w11, fmaf(xv.z, w12, fmaf(xv.w, w13, acc1[r]))));
        }
    }

#pragma unroll
    for (int r = 0; r < 32; ++r) {
        const long gr = row0 + r;
        if (gr < N) {
            if (hi == 0) {
                kbuf [gr * 128 + c0]       = cvt<T>(acc0[r] + b0);
                qvbuf[gr * 256 + 128 + c0] = cvt<T>(acc1[r] + b1);
            } else {
                qvbuf[gr * 256 + c0]       = cvt<T>(acc0[r] + b0);
                agg  [gr * 128 + c0]       = acc1[r];
            }
        }
    }
}

__global__ __launch_bounds__(256) void zero_kernel(int* __restrict__ p, int n) {
    const int i = blockIdx.x * 256 + threadIdx.x;
    if (i < n) p[i] = 0;
}

__global__ __launch_bounds__(256) void hist_kernel(
    const int* __restrict__ ei, int* __restrict__ deg, int E)
{
    const int e = blockIdx.x * 256 + threadIdx.x;
    if (e < E) atomicAdd(&deg[ei[E + e]], 1);
}

__global__ __launch_bounds__(1024) void scanA_kernel(
    const int* __restrict__ deg, int* __restrict__ off,
    int* __restrict__ bsum, int N)
{
    __shared__ int sm[1024];
    const int t = threadIdx.x;
    const int i = blockIdx.x * 1024 + t;
    const int v = (i < N) ? deg[i] : 0;
    int x = v;
    sm[t] = x;
    __syncthreads();
#pragma unroll
    for (int ofs = 1; ofs < 1024; ofs <<= 1) {
        const int y = (t >= ofs) ? sm[t - ofs] : 0;
        __syncthreads();
        x += y;
        sm[t] = x;
        __syncthreads();
    }
    if (i < N) off[i] = x - v;
    if (t == 1023) bsum[blockIdx.x] = x;
}

__global__ __launch_bounds__(1024) void scanB_kernel(int* __restrict__ bsum, int nb)
{
    __shared__ int sm[1024];
    const int t = threadIdx.x;
    const int v = (t < nb) ? bsum[t] : 0;
    int x = v;
    sm[t] = x;
    __syncthreads();
#pragma unroll
    for (int ofs = 1; ofs < 1024; ofs <<= 1) {
        const int y = (t >= ofs) ? sm[t - ofs] : 0;
        __syncthreads();
        x += y;
        sm[t] = x;
        __syncthreads();
    }
    if (t < nb) bsum[t] = x - v;
}

__global__ __launch_bounds__(256) void scanC_kernel(
    int* __restrict__ off, int* __restrict__ cursor,
    const int* __restrict__ bsum, int N)
{
    const int i = blockIdx.x * 256 + threadIdx.x;
    if (i < N) {
        const int o = off[i] + bsum[i >> 10];
        off[i]    = o;
        cursor[i] = o;
    }
}

__global__ __launch_bounds__(256) void scatter_kernel(
    const int* __restrict__ ei, int* __restrict__ cursor,
    int* __restrict__ ssrc, int E)
{
    const int e = blockIdx.x * 256 + threadIdx.x;
    if (e >= E) return;
    const int s = ei[e];
    const int d = ei[E + e];
    const int pos = atomicAdd(&cursor[d], 1);
    ssrc[pos] = s;
}

template <typename T>
__global__ __launch_bounds__(256) void gather_kernel(
    const int* __restrict__ off, const int* __restrict__ deg,
    const int* __restrict__ ssrc,
    const T* __restrict__ kbuf, const T* __restrict__ qvbuf,
    float* __restrict__ agg, int N)
{
    const int n = blockIdx.x * 4 + (threadIdx.x >> 6);
    if (n >= N) return;
    const int lane = threadIdx.x & 63;
    const int c = lane << 1;

    const int dg = deg[n];
    if (dg == 0) return;
    const int s0 = off[n];
    const int s1 = s0 + dg;

    const float2 k2 = ld2<T>(&kbuf[(long)n * 128 + c]);
    float a0 = 0.f, a1 = 0.f, b0 = 0.f, b1 = 0.f;

    int e = s0;
    for (; e + 4 <= s1; e += 4) {
        const long sa = ssrc[e + 0];
        const long sb = ssrc[e + 1];
        const long sc = ssrc[e + 2];
        const long sd = ssrc[e + 3];
        const float2 qa = ld2<T>(&qvbuf[sa * 256 + c]);
        const float2 va = ld2<T>(&qvbuf[sa * 256 + 128 + c]);
        const float2 qb = ld2<T>(&qvbuf[sb * 256 + c]);
        const float2 vb = ld2<T>(&qvbuf[sb * 256 + 128 + c]);
        const float2 qc = ld2<T>(&qvbuf[sc * 256 + c]);
        const float2 vc = ld2<T>(&qvbuf[sc * 256 + 128 + c]);
        const float2 qd = ld2<T>(&qvbuf[sd * 256 + c]);
        const float2 vd = ld2<T>(&qvbuf[sd * 256 + 128 + c]);
        a0 = fmaf(fmaxf(k2.x + qa.x, 0.f), va.x, a0);
        a1 = fmaf(fmaxf(k2.y + qa.y, 0.f), va.y, a1);
        b0 = fmaf(fmaxf(k2.x + qb.x, 0.f), vb.x, b0);
        b1 = fmaf(fmaxf(k2.y + qb.y, 0.f), vb.y, b1);
        a0 = fmaf(fmaxf(k2.x + qc.x, 0.f), vc.x, a0);
        a1 = fmaf(fmaxf(k2.y + qc.y, 0.f), vc.y, a1);
        b0 = fmaf(fmaxf(k2.x + qd.x, 0.f), vd.x, b0);
        b1 = fmaf(fmaxf(k2.y + qd.y, 0.f), vd.y, b1);
    }
    for (; e < s1; ++e) {
        const long s = ssrc[e];
        const float2 q = ld2<T>(&qvbuf[s * 256 + c]);
        const float2 v = ld2<T>(&qvbuf[s * 256 + 128 + c]);
        a0 = fmaf(fmaxf(k2.x + q.x, 0.f), v.x, a0);
        a1 = fmaf(fmaxf(k2.y + q.y, 0.f), v.y, a1);
    }

    float2* ap = reinterpret_cast<float2*>(&agg[(long)n * 128 + c]);
    const float2 old = *ap;
    *ap = make_float2(old.x + a0 + b0, old.y + a1 + b1);
}

template <typename T>
__global__ __launch_bounds__(256) void edge_kernel(
    const int* __restrict__ ei,
    const T* __restrict__ kbuf, const T* __restrict__ qvbuf,
    float* __restrict__ agg, int E)
{
    const int g = (blockIdx.x << 3) + (threadIdx.x >> 5);
    if (g >= E) return;
    const int lane = threadIdx.x & 31;
    const long src = (long)ei[g];
    const long dst = (long)ei[E + g];
    const int c = lane << 2;

    float kd[4], qs[4], vs[4];
    if constexpr (sizeof(T) == 4) {
        const float4 a = *reinterpret_cast<const float4*>(&kbuf[dst * 128 + c]);
        const float4 b = *reinterpret_cast<const float4*>(&qvbuf[src * 256 + c]);
        const float4 d = *reinterpret_cast<const float4*>(&qvbuf[src * 256 + 128 + c]);
        kd[0] = a.x; kd[1] = a.y; kd[2] = a.z; kd[3] = a.w;
        qs[0] = b.x; qs[1] = b.y; qs[2] = b.z; qs[3] = b.w;
        vs[0] = d.x; vs[1] = d.y; vs[2] = d.z; vs[3] = d.w;
    } else {
        const ushort4 a = *reinterpret_cast<const ushort4*>(&kbuf[dst * 128 + c]);
        const ushort4 b = *reinterpret_cast<const ushort4*>(&qvbuf[src * 256 + c]);
        const ushort4 d = *reinterpret_cast<const ushort4*>(&qvbuf[src * 256 + 128 + c]);
        kd[0] = bf2f(a.x); kd[1] = bf2f(a.y); kd[2] = bf2f(a.z); kd[3] = bf2f(a.w);
        qs[0] = bf2f(b.x); qs[1] = bf2f(b.y); qs[2] = bf2f(b.z); qs[3] = bf2f(b.w);
        vs[0] = bf2f(d.x); vs[1] = bf2f(d.y); vs[2] = bf2f(d.z); vs[3] = bf2f(d.w);
    }

    float* p = agg + dst * 128 + c;
#pragma unroll
    for (int j = 0; j < 4; ++j) {
        const float m = fmaxf(kd[j] + qs[j], 0.f) * vs[j];
        unsafeAtomicAdd(p + j, m);
    }
}

__global__ __launch_bounds__(64) void out_kernel(
    const float* agg, const float* __restrict__ bconv,
    const float* __restrict__ Wlin, const float* __restrict__ blin,
    float* out, int N)
{
    __shared__ float xt[32][DD];
    const int row0 = blockIdx.x * 32;
    const int t = threadIdx.x;

    for (int i = t; i < 32 * (DD / 4); i += 64) {
        const int r  = i >> 5;
        const int c4 = (i & 31) << 2;
        const int gr = row0 + r;
        float4 a = make_float4(0.f, 0.f, 0.f, 0.f);
        if (gr < N) a = *reinterpret_cast<const float4*>(&agg[(long)gr * DD + c4]);
        const float4 b = *reinterpret_cast<const float4*>(&bconv[c4]);
        float4 v;
        const float x0 = a.x + b.x; v.x = x0 >= 0.f ? x0 : 0.01f * x0;
        const float x1 = a.y + b.y; v.y = x1 >= 0.f ? x1 : 0.01f * x1;
        const float x2 = a.z + b.z; v.z = x2 >= 0.f ? x2 : 0.01f * x2;
        const float x3 = a.w + b.w; v.w = x3 >= 0.f ? x3 : 0.01f * x3;
        *reinterpret_cast<float4*>(&xt[r][c4]) = v;
    }
    __syncthreads();

    const int c0 = t;
    const int c1 = t + 64;
    float acc0[32], acc1[32];
#pragma unroll
    for (int r = 0; r < 32; ++r) { acc0[r] = 0.f; acc1[r] = 0.f; }

    for (int k4 = 0; k4 < DD; k4 += 4) {
        const float w00 = Wlin[(k4 + 0) * DD + c0];
        const float w01 = Wlin[(k4 + 1) * DD + c0];
        const float w02 = Wlin[(k4 + 2) * DD + c0];
        const float w03 = Wlin[(k4 + 3) * DD + c0];
        const float w10 = Wlin[(k4 + 0) * DD + c1];
        const float w11 = Wlin[(k4 + 1) * DD + c1];
        const float w12 = Wlin[(k4 + 2) * DD + c1];
        const float w13 = Wlin[(k4 + 3) * DD + c1];
#pragma unroll
        for (int r = 0; r < 32; ++r) {
            const float4 xv = *reinterpret_cast<const float4*>(&xt[r][k4]);
            acc0[r] = fmaf(xv.x, w00, fmaf(xv.y, w01, fmaf(xv.z, w02, fmaf(xv.w, w03, acc0[r]))));
            acc1[r] = fmaf(xv.x, w10, fmaf(xv.y, w11, fmaf(xv.z, w12, fmaf(xv.w, w13, acc1[r]))));
        }
    }

    const float bb0 = blin[c0];
    const float bb1 = blin[c1];
#pragma unroll
    for (int r = 0; r < 32; ++r) {
        const long gr = row0 + r;
        if (gr < N) {
            out[gr * DD + c0] = acc0[r] + bb0;
            out[gr * DD + c1] = acc1[r] + bb1;
        }
    }
}

// ---------------------------------------------------------------------------
extern "C" void kernel_launch(void* const* d_in, const int* in_sizes, int n_in,
                              void* d_out, int out_size, void* d_ws, size_t ws_size,
                              hipStream_t stream)
{
    const float* x     = (const float*)d_in[0];
    const int*   ei    = (const int*)d_in[1];      // int32 (harness converts int64 -> int32)
    const float* Wk    = (const float*)d_in[2];
    const float* bk    = (const float*)d_in[3];
    const float* Wq    = (const float*)d_in[4];
    const float* bq    = (const float*)d_in[5];
    const float* Wv    = (const float*)d_in[6];
    const float* bv    = (const float*)d_in[7];
    const float* Ws    = (const float*)d_in[8];
    const float* bconv = (const float*)d_in[9];
    const float* Wlin  = (const float*)d_in[10];
    const float* blin  = (const float*)d_in[11];

    const int N = in_sizes[0] / DD;
    const int E = in_sizes[1] / 2;

    float* aggf = (float*)d_out;                 // agg lives in d_out
    const int nblk    = (N + 31) / 32;
    const int mblk    = (N + 63) / 64;           // MFMA kernels: 64 rows/block
    const int eblk1   = (E + 255) / 256;
    const int nblk1   = (N + 255) / 256;
    const int gblk    = (N + 3) / 4;
    const int nchunks = (N + 1023) / 1024;       // <= 1024
    const int hblk    = (E + 511) / 512;         // hist tail blocks (512 thr)

    const int bsum_pad = (nchunks + 255) & ~255;

    // fast-path CSR layout: deg | off | cnt2 | bsum(bsum_pad) | done(256) | ssrc
    size_t csrF_ints = (size_t)3 * N + bsum_pad + 256 + E;
    csrF_ints = (csrF_ints + 3) & ~(size_t)3;
    const size_t csrF_bytes = csrF_ints * sizeof(int);

    // fallback CSR layout (round-5): deg | off | cursor | bsum | ssrc
    size_t csrO_ints = (size_t)3 * N + bsum_pad + E;
    csrO_ints = (csrO_ints + 3) & ~(size_t)3;
    const size_t csrO_bytes = csrO_ints * sizeof(int);

    const size_t projPK   = (size_t)N * (128 + 256) * sizeof(unsigned short); // k bf16 + qv packed bf16
    const size_t projF32  = (size_t)N * 384 * sizeof(float);
    const size_t projBF16 = (size_t)N * 384 * sizeof(unsigned short);
    const size_t wsplit   = (size_t)5 * 2048 * 8 * sizeof(unsigned short); // 160KB

    if (ws_size >= csrF_bytes + projPK + wsplit) {
        // ---- MFMA + packed-bf16-gather fast path (6 launches) ----
        int* deg  = (int*)d_ws;
        int* off  = deg + N;
        int* cnt2 = off + N;
        int* bsum = cnt2 + N;
        int* done = bsum + bsum_pad;
        int* ssrc = done + 256;
        unsigned short* kbuf = (unsigned short*)((char*)d_ws + csrF_bytes);
        unsigned short* qvpk = kbuf + (size_t)N * 128;
        unsigned short* whi  = qvpk + (size_t)N * 256;

        const int swblk = (N + 255) / 256;       // covers zeroing and frags
        split_w_kernel<<<swblk, 256, 0, stream>>>(Wk, Wq, Wv, Ws, Wlin, whi,
                                                  deg, cnt2, done, N);
        proj_mfma_kernel<<<mblk + hblk, 512, 0, stream>>>(x, whi, bk, bq, bv,
                                                          kbuf, qvpk, aggf,
                                                          ei, deg, mblk, E, N);
        scanAB_kernel<<<nchunks, 1024, 0, stream>>>(deg, off, bsum, done, N, nchunks);
        scatter2_kernel<<<eblk1, 256, 0, stream>>>(ei, off, bsum, cnt2, ssrc, E);
        gather_packed_kernel<<<gblk, 256, 0, stream>>>(off, bsum, deg, ssrc, kbuf, qvpk, aggf, N);
        out_mfma_kernel<<<mblk, 512, 0, stream>>>(aggf, bconv, whi, blin, (float*)d_out, N);
    } else if (ws_size >= csrO_bytes + projF32) {
        // ---- round-5 proven VALU path ----
        int* deg    = (int*)d_ws;
        int* off    = deg + N;
        int* cursor = off + N;
        int* bsum   = cursor + N;
        int* ssrc   = bsum + bsum_pad;
        float* kbuf  = (float*)((char*)d_ws + csrO_bytes);
        float* qvbuf = kbuf + (size_t)N * 128;

        proj_kernel<float><<<nblk, 256, 0, stream>>>(x, Wk, bk, Wq, bq, Wv, bv, Ws,
                                                     kbuf, qvbuf, aggf, N);
        zero_kernel<<<nblk1, 256, 0, stream>>>(deg, N);
        hist_kernel<<<eblk1, 256, 0, stream>>>(ei, deg, E);
        scanA_kernel<<<nchunks, 1024, 0, stream>>>(deg, off, bsum, N);
        scanB_kernel<<<1, 1024, 0, stream>>>(bsum, nchunks);
        scanC_kernel<<<nblk1, 256, 0, stream>>>(off, cursor, bsum, N);
        scatter_kernel<<<eblk1, 256, 0, stream>>>(ei, cursor, ssrc, E);
        gather_kernel<float><<<gblk, 256, 0, stream>>>(off, deg, ssrc, kbuf, qvbuf, aggf, N);
        out_kernel<<<nblk, 64, 0, stream>>>(aggf, bconv, Wlin, blin, (float*)d_out, N);
    } else if (ws_size >= csrO_bytes + projBF16) {
        int* deg    = (int*)d_ws;
        int* off    = deg + N;
        int* cursor = off + N;
        int* bsum   = cursor + N;
        int* ssrc   = bsum + bsum_pad;
        unsigned short* kbuf  = (unsigned short*)((char*)d_ws + csrO_bytes);
        unsigned short* qvbuf = kbuf + (size_t)N * 128;

        proj_kernel<unsigned short><<<nblk, 256, 0, stream>>>(x, Wk, bk, Wq, bq, Wv, bv, Ws,
                                                              kbuf, qvbuf, aggf, N);
        zero_kernel<<<nblk1, 256, 0, stream>>>(deg, N);
        hist_kernel<<<eblk1, 256, 0, stream>>>(ei, deg, E);
        scanA_kernel<<<nchunks, 1024, 0, stream>>>(deg, off, bsum, N);
        scanB_kernel<<<1, 1024, 0, stream>>>(bsum, nchunks);
        scanC_kernel<<<nblk1, 256, 0, stream>>>(off, cursor, bsum, N);
        scatter_kernel<<<eblk1, 256, 0, stream>>>(ei, cursor, ssrc, E);
        gather_kernel<unsigned short><<<gblk, 256, 0, stream>>>(off, deg, ssrc, kbuf, qvbuf, aggf, N);
        out_kernel<<<nblk, 64, 0, stream>>>(aggf, bconv, Wlin, blin, (float*)d_out, N);
    } else if (ws_size >= projBF16) {
        unsigned short* kbuf  = (unsigned short*)d_ws;
        unsigned short* qvbuf = kbuf + (size_t)N * 128;
        const int eblk8 = (E + 7) / 8;
        proj_kernel<unsigned short><<<nblk, 256, 0, stream>>>(x, Wk, bk, Wq, bq, Wv, bv, Ws,
                                                              kbuf, qvbuf, aggf, N);
        edge_kernel<unsigned short><<<eblk8, 256, 0, stream>>>(ei, kbuf, qvbuf, aggf, E);
        out_kernel<<<nblk, 64, 0, stream>>>(aggf, bconv, Wlin, blin, (float*)d_out, N);
    } else {
        hipMemsetAsync(d_out, 0, (size_t)out_size * sizeof(float), stream);
        return;
    }
}

// Round 20
// 212.078 us; speedup vs baseline: 1.0213x; 1.0213x over previous
//
#include <hip/hip_runtime.h>

#define DD 128

typedef __attribute__((ext_vector_type(8))) short bf16x8;
typedef __attribute__((ext_vector_type(4))) float f32x4;

// ---- bf16 helpers (RNE) ----------------------------------------------------
__device__ inline unsigned short f2bf(float f) {
    unsigned int u = __float_as_uint(f);
    u += 0x7FFFu + ((u >> 16) & 1u);
    return (unsigned short)(u >> 16);
}
__device__ inline float bf2f(unsigned short s) {
    return __uint_as_float(((unsigned int)s) << 16);
}

template <typename T> __device__ inline T cvt(float f);
template <> __device__ inline float cvt<float>(float f) { return f; }
template <> __device__ inline unsigned short cvt<unsigned short>(float f) { return f2bf(f); }

template <typename T> __device__ inline float2 ld2(const T* p);
template <> __device__ inline float2 ld2<float>(const float* p) {
    return *reinterpret_cast<const float2*>(p);
}
template <> __device__ inline float2 ld2<unsigned short>(const unsigned short* p) {
    const ushort2 u = *reinterpret_cast<const ushort2*>(p);
    return make_float2(bf2f(u.x), bf2f(u.y));
}

// ---------------------------------------------------------------------------
// Plain-bf16 MFMA pipeline — FINAL (round-18 configuration, best: 214.0us).
// Round 20: round-19's out_mfma LDS epilogue REVERTED (216.6 vs 214.0 — fp32
// D-fragment stores are already 64B segments; staging overhead > gain).
// History: 1541 (atomics) -> 482 (CSR) -> 401 (par scan) -> 333 (wsplit)
//   -> 278 (packed bf16 gather) -> 258 (plain bf16 MFMA) -> 230 (8-wave)
//   -> 227 (kbuf bf16) -> 214 (proj LDS-staged coalesced epilogue).
// ---------------------------------------------------------------------------

// One-shot: weights -> bf16 B-fragment layout; also zeroes deg/cnt2/done.
__global__ __launch_bounds__(256) void split_w_kernel(
    const float* __restrict__ W0, const float* __restrict__ W1,
    const float* __restrict__ W2, const float* __restrict__ W3,
    const float* __restrict__ W4,
    unsigned short* __restrict__ whi,
    int* __restrict__ deg, int* __restrict__ cnt2, int* __restrict__ done,
    int N)
{
    const int gid = blockIdx.x * 256 + threadIdx.x;
    if (gid < N) { deg[gid] = 0; cnt2[gid] = 0; }
    if (gid == 0) *done = 0;

    const int idx = gid;                              // 5 * 2048 frags
    if (idx >= 5 * 2048) return;
    const int mat  = idx >> 11;
    const int rem  = idx & 2047;
    const int ks   = rem >> 9;
    const int nt   = (rem >> 6) & 7;
    const int lane = rem & 63;
    const int lr = lane & 15, lg = lane >> 4;
    const float* __restrict__ W = mat == 0 ? W0 : mat == 1 ? W1 : mat == 2 ? W2
                                 : mat == 3 ? W3 : W4;
    const int n = nt * 16 + lr;
    bf16x8 h8;
#pragma unroll
    for (int r = 0; r < 8; ++r) {
        const int k = ks * 32 + lg * 8 + r;
        h8[r] = (short)f2bf(W[k * DD + n]);
    }
    *reinterpret_cast<bf16x8*>(&whi[(long)idx * 8]) = h8;
}

// Stage 64 rows x 128 cols of fp32 A as bf16 fragments in LDS (512 threads).
template <bool XFORM>
__device__ inline void stage_rows512(const float* __restrict__ src,
                                     const float* __restrict__ addv,
                                     int row0, int N, int t,
                                     unsigned short* __restrict__ ldsA)
{
    const int m  = t >> 3;            // 0..63 local row
    const int gr = row0 + m;
#pragma unroll
    for (int j = 0; j < 2; ++j) {
        const int o = (t & 7) + j * 8;   // k-octet 0..15
        float v[8];
        if (gr < N) {
            const float4 a = *reinterpret_cast<const float4*>(&src[(long)gr * DD + o * 8]);
            const float4 b = *reinterpret_cast<const float4*>(&src[(long)gr * DD + o * 8 + 4]);
            v[0] = a.x; v[1] = a.y; v[2] = a.z; v[3] = a.w;
            v[4] = b.x; v[5] = b.y; v[6] = b.z; v[7] = b.w;
        } else {
#pragma unroll
            for (int e = 0; e < 8; ++e) v[e] = 0.f;
        }
        if (XFORM) {   // leaky_relu(src + addv) fused into staging
#pragma unroll
            for (int e = 0; e < 8; ++e) {
                const float s = v[e] + addv[o * 8 + e];
                v[e] = s >= 0.f ? s : 0.01f * s;
            }
        }
        bf16x8 h8;
#pragma unroll
        for (int e = 0; e < 8; ++e) h8[e] = (short)f2bf(v[e]);
        const int rt   = m >> 4;
        const int ks   = o >> 2;
        const int lane = (m & 15) + (o & 3) * 16;
        const int base = ((rt * 4 + ks) * 64 + lane) * 8;
        *reinterpret_cast<bf16x8*>(&ldsA[base]) = h8;
    }
}

// ---------------------------------------------------------------------------
// Kernel (MFMA, 512 thr / 8 waves): fused node projections + histogram tail.
// Epilogue staged in LDS for coalesced writes (round-18 validated: +13us).
// ---------------------------------------------------------------------------
__global__ __launch_bounds__(512) void proj_mfma_kernel(
    const float* __restrict__ x,
    const unsigned short* __restrict__ whi,
    const float* __restrict__ bk, const float* __restrict__ bq,
    const float* __restrict__ bv,
    unsigned short* __restrict__ kbuf, unsigned short* __restrict__ qvpk,
    float* __restrict__ agg,
    const int* __restrict__ ei, int* __restrict__ deg,
    int projBlocks, int E, int N)
{
    __shared__ unsigned short smem[16384];        // 32 KB multi-purpose
    const int t = threadIdx.x;

    if (blockIdx.x >= projBlocks) {               // histogram role
        const int e = (blockIdx.x - projBlocks) * 512 + t;
        if (e < E) atomicAdd(&deg[ei[E + e]], 1);
        return;
    }

    const int row0 = blockIdx.x * 64;
    stage_rows512<false>(x, nullptr, row0, N, t, smem);   // uses first 16KB
    __syncthreads();

    const int wv   = t >> 6;
    const int mat  = wv >> 1;
    const int cc   = wv & 1;
    const int lane = t & 63;
    const int lr = lane & 15;
    const int lg = lane >> 4;

    f32x4 acc[4][4];
#pragma unroll
    for (int rt = 0; rt < 4; ++rt)
#pragma unroll
        for (int ct = 0; ct < 4; ++ct) acc[rt][ct] = (f32x4){0.f, 0.f, 0.f, 0.f};

#pragma unroll
    for (int ks = 0; ks < 4; ++ks) {
        bf16x8 A[4];
#pragma unroll
        for (int rt = 0; rt < 4; ++rt)
            A[rt] = *reinterpret_cast<const bf16x8*>(&smem[((rt * 4 + ks) * 64 + lane) * 8]);
#pragma unroll
        for (int ct = 0; ct < 4; ++ct) {
            const long fb = ((long)((mat * 4 + ks) * 8 + (cc * 4 + ct)) * 64 + lane) * 8;
            const bf16x8 B = *reinterpret_cast<const bf16x8*>(&whi[fb]);
#pragma unroll
            for (int rt = 0; rt < 4; ++rt)
                acc[rt][ct] = __builtin_amdgcn_mfma_f32_16x16x32_bf16(A[rt], B, acc[rt][ct], 0, 0, 0);
        }
    }
    __syncthreads();   // ldsA reads complete; smem free for staging

    // ---- Phase 1: Q/V -> smem[64][256] bf16, then coalesced copy ----
    if (mat == 1 || mat == 2) {
        const float* bias2 = (mat == 1) ? bq : bv;
        const int sub = mat - 1;
#pragma unroll
        for (int ct = 0; ct < 4; ++ct) {
            const int n_l = cc * 64 + ct * 16 + lr;
            const float bb = bias2[n_l];
#pragma unroll
            for (int rt = 0; rt < 4; ++rt)
#pragma unroll
                for (int r = 0; r < 4; ++r) {
                    const int m = rt * 16 + lg * 4 + r;
                    smem[m * 256 + 2 * n_l + sub] = f2bf(acc[rt][ct][r] + bb);
                }
        }
    }
    __syncthreads();
    {
        const int row = t >> 3;
        const int c0  = (t & 7) * 32;
        if (row0 + row < N) {
            const bf16x8* sp = reinterpret_cast<const bf16x8*>(&smem[row * 256 + c0]);
            bf16x8* dp = reinterpret_cast<bf16x8*>(&qvpk[(long)(row0 + row) * 256 + c0]);
#pragma unroll
            for (int i = 0; i < 4; ++i) dp[i] = sp[i];
        }
    }
    __syncthreads();

    // ---- Phase 2: K -> smem[64][128] bf16, then coalesced copy ----
    if (mat == 0) {
#pragma unroll
        for (int ct = 0; ct < 4; ++ct) {
            const int n_l = cc * 64 + ct * 16 + lr;
            const float bb = bk[n_l];
#pragma unroll
            for (int rt = 0; rt < 4; ++rt)
#pragma unroll
                for (int r = 0; r < 4; ++r) {
                    const int m = rt * 16 + lg * 4 + r;
                    smem[m * 128 + n_l] = f2bf(acc[rt][ct][r] + bb);
                }
        }
    }
    __syncthreads();
    {
        const int row = t >> 3;
        const int c0  = (t & 7) * 16;
        if (row0 + row < N) {
            const bf16x8* sp = reinterpret_cast<const bf16x8*>(&smem[row * 128 + c0]);
            bf16x8* dp = reinterpret_cast<bf16x8*>(&kbuf[(long)(row0 + row) * 128 + c0]);
            dp[0] = sp[0]; dp[1] = sp[1];
        }
    }
    __syncthreads();

    // ---- Phase 3: Skip/agg -> smem[64][128] fp32 (32KB), coalesced copy ----
    float* smf = reinterpret_cast<float*>(smem);
    if (mat == 3) {
#pragma unroll
        for (int ct = 0; ct < 4; ++ct) {
            const int n_l = cc * 64 + ct * 16 + lr;
#pragma unroll
            for (int rt = 0; rt < 4; ++rt)
#pragma unroll
                for (int r = 0; r < 4; ++r) {
                    const int m = rt * 16 + lg * 4 + r;
                    smf[m * 128 + n_l] = acc[rt][ct][r];
                }
        }
    }
    __syncthreads();
    {
        const int row = t >> 3;
        const int c0  = (t & 7) * 16;
        if (row0 + row < N) {
            const float4* sp = reinterpret_cast<const float4*>(&smf[row * 128 + c0]);
            float4* dp = reinterpret_cast<float4*>(&agg[(long)(row0 + row) * 128 + c0]);
#pragma unroll
            for (int i = 0; i < 4; ++i) dp[i] = sp[i];
        }
    }
}

// ---------------------------------------------------------------------------
// Fused scan: per-chunk scan + chunk totals; last block scans bsum in place.
// ---------------------------------------------------------------------------
__global__ __launch_bounds__(1024) void scanAB_kernel(
    const int* __restrict__ deg, int* __restrict__ off,
    int* __restrict__ bsum, int* __restrict__ done, int N, int nb)
{
    __shared__ int sm[1024];
    __shared__ int amLast;
    const int t = threadIdx.x;
    const int i = blockIdx.x * 1024 + t;
    const int v = (i < N) ? deg[i] : 0;
    int x = v;
    sm[t] = x;
    __syncthreads();
#pragma unroll
    for (int ofs = 1; ofs < 1024; ofs <<= 1) {
        const int y = (t >= ofs) ? sm[t - ofs] : 0;
        __syncthreads();
        x += y;
        sm[t] = x;
        __syncthreads();
    }
    if (i < N) off[i] = x - v;
    if (t == 1023) { bsum[blockIdx.x] = x; __threadfence(); }
    __syncthreads();
    if (t == 0) amLast = (atomicAdd(done, 1) == (int)gridDim.x - 1) ? 1 : 0;
    __syncthreads();
    if (!amLast) return;

    const int vb = (t < nb) ? atomicAdd(&bsum[t], 0) : 0;
    int xb = vb;
    sm[t] = xb;
    __syncthreads();
#pragma unroll
    for (int ofs = 1; ofs < 1024; ofs <<= 1) {
        const int y = (t >= ofs) ? sm[t - ofs] : 0;
        __syncthreads();
        xb += y;
        sm[t] = xb;
        __syncthreads();
    }
    if (t < nb) bsum[t] = xb - vb;
}

// scatter: pos = off[d] + bsum[chunk] + cnt2[d]++
__global__ __launch_bounds__(256) void scatter2_kernel(
    const int* __restrict__ ei,
    const int* __restrict__ off, const int* __restrict__ bsum,
    int* __restrict__ cnt2, int* __restrict__ ssrc, int E)
{
    const int e = blockIdx.x * 256 + threadIdx.x;
    if (e >= E) return;
    const int s = ei[e];
    const int d = ei[E + e];
    const int pos = off[d] + bsum[d >> 10] + atomicAdd(&cnt2[d], 1);
    ssrc[pos] = s;
}

// ---------------------------------------------------------------------------
// Kernel (MFMA, 512 thr / 8 waves): out = leaky(agg + b_conv) @ Wlin + blin.
// agg aliases out. Direct D-fragment stores (round-18 config; LDS-staged
// variant measured slower in round 19).
// ---------------------------------------------------------------------------
__global__ __launch_bounds__(512) void out_mfma_kernel(
    const float* agg, const float* __restrict__ bconv,
    const unsigned short* __restrict__ whi,
    const float* __restrict__ blin,
    float* out, int N)
{
    __shared__ unsigned short ldsA[16 * 64 * 8];
    const int t = threadIdx.x;
    const int row0 = blockIdx.x * 64;

    stage_rows512<true>(agg, bconv, row0, N, t, ldsA);
    __syncthreads();

    const int wv   = t >> 6;
    const int lane = t & 63;
    const int lr = lane & 15;
    const int lg = lane >> 4;

    f32x4 acc[4];
#pragma unroll
    for (int rt = 0; rt < 4; ++rt) acc[rt] = (f32x4){0.f, 0.f, 0.f, 0.f};

#pragma unroll
    for (int ks = 0; ks < 4; ++ks) {
        bf16x8 A[4];
#pragma unroll
        for (int rt = 0; rt < 4; ++rt)
            A[rt] = *reinterpret_cast<const bf16x8*>(&ldsA[((rt * 4 + ks) * 64 + lane) * 8]);
        const long fb = ((long)((16 + ks) * 8 + wv) * 64 + lane) * 8;
        const bf16x8 B = *reinterpret_cast<const bf16x8*>(&whi[fb]);
#pragma unroll
        for (int rt = 0; rt < 4; ++rt)
            acc[rt] = __builtin_amdgcn_mfma_f32_16x16x32_bf16(A[rt], B, acc[rt], 0, 0, 0);
    }

    const int n = wv * 16 + lr;
    const float bb = blin[n];
#pragma unroll
    for (int rt = 0; rt < 4; ++rt) {
#pragma unroll
        for (int r = 0; r < 4; ++r) {
            const int m = row0 + rt * 16 + lg * 4 + r;
            if (m < N) out[(long)m * 128 + n] = acc[rt][r] + bb;
        }
    }
}

// ---------------------------------------------------------------------------
// Gather (packed): one wave per dst node; lane owns channels (2L, 2L+1).
// 8-edge unroll (round-11 proven). kbuf bf16 (round-17 validated).
// ---------------------------------------------------------------------------
__global__ __launch_bounds__(256) void gather_packed_kernel(
    const int* __restrict__ off, const int* __restrict__ bsum,
    const int* __restrict__ deg, const int* __restrict__ ssrc,
    const unsigned short* __restrict__ kbuf, const unsigned short* __restrict__ qvpk,
    float* __restrict__ agg, int N)
{
    const int n = blockIdx.x * 4 + (threadIdx.x >> 6);
    if (n >= N) return;
    const int lane = threadIdx.x & 63;

    const int dg = deg[n];
    if (dg == 0) return;
    const int s0 = off[n] + bsum[n >> 10];
    const int s1 = s0 + dg;

    const ushort2 ku = *reinterpret_cast<const ushort2*>(&kbuf[(long)n * 128 + lane * 2]);
    const float k0 = bf2f(ku.x), k1 = bf2f(ku.y);
    float a0 = 0.f, a1 = 0.f, b0 = 0.f, b1 = 0.f;

    int e = s0;
    for (; e + 8 <= s1; e += 8) {
        int s[8];
#pragma unroll
        for (int j = 0; j < 8; ++j) s[j] = ssrc[e + j];
        ushort4 u[8];
#pragma unroll
        for (int j = 0; j < 8; ++j)
            u[j] = *reinterpret_cast<const ushort4*>(&qvpk[(long)s[j] * 256 + lane * 4]);
#pragma unroll
        for (int j = 0; j < 8; ++j) {
            const float q0 = bf2f(u[j].x), v0 = bf2f(u[j].y);
            const float q1 = bf2f(u[j].z), v1 = bf2f(u[j].w);
            if (j & 1) {
                b0 = fmaf(fmaxf(k0 + q0, 0.f), v0, b0);
                b1 = fmaf(fmaxf(k1 + q1, 0.f), v1, b1);
            } else {
                a0 = fmaf(fmaxf(k0 + q0, 0.f), v0, a0);
                a1 = fmaf(fmaxf(k1 + q1, 0.f), v1, a1);
            }
        }
    }
    for (; e < s1; ++e) {
        const int s = ssrc[e];
        const ushort4 u = *reinterpret_cast<const ushort4*>(&qvpk[(long)s * 256 + lane * 4]);
        a0 = fmaf(fmaxf(k0 + bf2f(u.x), 0.f), bf2f(u.y), a0);
        a1 = fmaf(fmaxf(k1 + bf2f(u.z), 0.f), bf2f(u.w), a1);
    }

    float2* ap = reinterpret_cast<float2*>(&agg[(long)n * 128 + lane * 2]);
    const float2 old = *ap;
    *ap = make_float2(old.x + a0 + b0, old.y + a1 + b1);
}

// ===========================================================================
// Fallback-path kernels (unchanged, proven round-5 structure)
// ===========================================================================
template <typename T>
__global__ __launch_bounds__(256) void proj_kernel(
    const float* __restrict__ x,
    const float* __restrict__ Wk, const float* __restrict__ bk,
    const float* __restrict__ Wq, const float* __restrict__ bq,
    const float* __restrict__ Wv, const float* __restrict__ bv,
    const float* __restrict__ Ws,
    T* __restrict__ kbuf, T* __restrict__ qvbuf, float* __restrict__ agg,
    int N)
{
    __shared__ float xt[32][DD];
    const int row0 = blockIdx.x * 32;
    const int t = threadIdx.x;

    for (int i = t; i < 32 * (DD / 4); i += 256) {
        const int r  = i >> 5;
        const int c4 = (i & 31) << 2;
        const int gr = row0 + r;
        float4 v = make_float4(0.f, 0.f, 0.f, 0.f);
        if (gr < N) v = *reinterpret_cast<const float4*>(&x[(long)gr * DD + c4]);
        *reinterpret_cast<float4*>(&xt[r][c4]) = v;
    }
    __syncthreads();

    const int c0 = t & 127;
    const int hi = t >> 7;
    const float* __restrict__ W0 = hi ? Wq : Wk;
    const float* __restrict__ W1 = hi ? Ws : Wv;
    const float b0 = hi ? bq[c0] : bk[c0];
    const float b1 = hi ? 0.f    : bv[c0];

    float acc0[32], acc1[32];
#pragma unroll
    for (int r = 0; r < 32; ++r) { acc0[r] = 0.f; acc1[r] = 0.f; }

    for (int k4 = 0; k4 < DD; k4 += 4) {
        const float w00 = W0[(k4 + 0) * DD + c0];
        const float w01 = W0[(k4 + 1) * DD + c0];
        const float w02 = W0[(k4 + 2) * DD + c0];
        const float w03 = W0[(k4 + 3) * DD + c0];
        const float w10 = W1[(k4 + 0) * DD + c0];
        const float w11 = W1[(k4 + 1) * DD + c0];
        const float w12 = W1[(k4 + 2) * DD + c0];
        const float w13 = W1[(k4 + 3) * DD + c0];
#pragma unroll
        for (int r = 0; r < 32; ++r) {
            const float4 xv = *reinterpret_cast<const float4*>(&xt[r][k4]);
            acc0[r] = fmaf(xv.x, w00, fmaf(xv.y, w01, fmaf(xv.z, w02, fmaf(xv.w, w03, acc0[r]))));
            acc1[r] = fmaf(xv.x, w10, fmaf(xv.y, w11, fmaf(xv.z, w12, fmaf(xv.w, w13, acc1[r]))));
        }
    }

#pragma unroll
    for (int r = 0; r < 32; ++r) {
        const long gr = row0 + r;
        if (gr < N) {
            if (hi == 0) {
                kbuf [gr * 128 + c0]       = cvt<T>(acc0[r] + b0);
                qvbuf[gr * 256 + 128 + c0] = cvt<T>(acc1[r] + b1);
            } else {
                qvbuf[gr * 256 + c0]       = cvt<T>(acc0[r] + b0);
                agg  [gr * 128 + c0]       = acc1[r];
            }
        }
    }
}

__global__ __launch_bounds__(256) void zero_kernel(int* __restrict__ p, int n) {
    const int i = blockIdx.x * 256 + threadIdx.x;
    if (i < n) p[i] = 0;
}

__global__ __launch_bounds__(256) void hist_kernel(
    const int* __restrict__ ei, int* __restrict__ deg, int E)
{
    const int e = blockIdx.x * 256 + threadIdx.x;
    if (e < E) atomicAdd(&deg[ei[E + e]], 1);
}

__global__ __launch_bounds__(1024) void scanA_kernel(
    const int* __restrict__ deg, int* __restrict__ off,
    int* __restrict__ bsum, int N)
{
    __shared__ int sm[1024];
    const int t = threadIdx.x;
    const int i = blockIdx.x * 1024 + t;
    const int v = (i < N) ? deg[i] : 0;
    int x = v;
    sm[t] = x;
    __syncthreads();
#pragma unroll
    for (int ofs = 1; ofs < 1024; ofs <<= 1) {
        const int y = (t >= ofs) ? sm[t - ofs] : 0;
        __syncthreads();
        x += y;
        sm[t] = x;
        __syncthreads();
    }
    if (i < N) off[i] = x - v;
    if (t == 1023) bsum[blockIdx.x] = x;
}

__global__ __launch_bounds__(1024) void scanB_kernel(int* __restrict__ bsum, int nb)
{
    __shared__ int sm[1024];
    const int t = threadIdx.x;
    const int v = (t < nb) ? bsum[t] : 0;
    int x = v;
    sm[t] = x;
    __syncthreads();
#pragma unroll
    for (int ofs = 1; ofs < 1024; ofs <<= 1) {
        const int y = (t >= ofs) ? sm[t - ofs] : 0;
        __syncthreads();
        x += y;
        sm[t] = x;
        __syncthreads();
    }
    if (t < nb) bsum[t] = x - v;
}

__global__ __launch_bounds__(256) void scanC_kernel(
    int* __restrict__ off, int* __restrict__ cursor,
    const int* __restrict__ bsum, int N)
{
    const int i = blockIdx.x * 256 + threadIdx.x;
    if (i < N) {
        const int o = off[i] + bsum[i >> 10];
        off[i]    = o;
        cursor[i] = o;
    }
}

__global__ __launch_bounds__(256) void scatter_kernel(
    const int* __restrict__ ei, int* __restrict__ cursor,
    int* __restrict__ ssrc, int E)
{
    const int e = blockIdx.x * 256 + threadIdx.x;
    if (e >= E) return;
    const int s = ei[e];
    const int d = ei[E + e];
    const int pos = atomicAdd(&cursor[d], 1);
    ssrc[pos] = s;
}

template <typename T>
__global__ __launch_bounds__(256) void gather_kernel(
    const int* __restrict__ off, const int* __restrict__ deg,
    const int* __restrict__ ssrc,
    const T* __restrict__ kbuf, const T* __restrict__ qvbuf,
    float* __restrict__ agg, int N)
{
    const int n = blockIdx.x * 4 + (threadIdx.x >> 6);
    if (n >= N) return;
    const int lane = threadIdx.x & 63;
    const int c = lane << 1;

    const int dg = deg[n];
    if (dg == 0) return;
    const int s0 = off[n];
    const int s1 = s0 + dg;

    const float2 k2 = ld2<T>(&kbuf[(long)n * 128 + c]);
    float a0 = 0.f, a1 = 0.f, b0 = 0.f, b1 = 0.f;

    int e = s0;
    for (; e + 4 <= s1; e += 4) {
        const long sa = ssrc[e + 0];
        const long sb = ssrc[e + 1];
        const long sc = ssrc[e + 2];
        const long sd = ssrc[e + 3];
        const float2 qa = ld2<T>(&qvbuf[sa * 256 + c]);
        const float2 va = ld2<T>(&qvbuf[sa * 256 + 128 + c]);
        const float2 qb = ld2<T>(&qvbuf[sb * 256 + c]);
        const float2 vb = ld2<T>(&qvbuf[sb * 256 + 128 + c]);
        const float2 qc = ld2<T>(&qvbuf[sc * 256 + c]);
        const float2 vc = ld2<T>(&qvbuf[sc * 256 + 128 + c]);
        const float2 qd = ld2<T>(&qvbuf[sd * 256 + c]);
        const float2 vd = ld2<T>(&qvbuf[sd * 256 + 128 + c]);
        a0 = fmaf(fmaxf(k2.x + qa.x, 0.f), va.x, a0);
        a1 = fmaf(fmaxf(k2.y + qa.y, 0.f), va.y, a1);
        b0 = fmaf(fmaxf(k2.x + qb.x, 0.f), vb.x, b0);
        b1 = fmaf(fmaxf(k2.y + qb.y, 0.f), vb.y, b1);
        a0 = fmaf(fmaxf(k2.x + qc.x, 0.f), vc.x, a0);
        a1 = fmaf(fmaxf(k2.y + qc.y, 0.f), vc.y, a1);
        b0 = fmaf(fmaxf(k2.x + qd.x, 0.f), vd.x, b0);
        b1 = fmaf(fmaxf(k2.y + qd.y, 0.f), vd.y, b1);
    }
    for (; e < s1; ++e) {
        const long s = ssrc[e];
        const float2 q = ld2<T>(&qvbuf[s * 256 + c]);
        const float2 v = ld2<T>(&qvbuf[s * 256 + 128 + c]);
        a0 = fmaf(fmaxf(k2.x + q.x, 0.f), v.x, a0);
        a1 = fmaf(fmaxf(k2.y + q.y, 0.f), v.y, a1);
    }

    float2* ap = reinterpret_cast<float2*>(&agg[(long)n * 128 + c]);
    const float2 old = *ap;
    *ap = make_float2(old.x + a0 + b0, old.y + a1 + b1);
}

template <typename T>
__global__ __launch_bounds__(256) void edge_kernel(
    const int* __restrict__ ei,
    const T* __restrict__ kbuf, const T* __restrict__ qvbuf,
    float* __restrict__ agg, int E)
{
    const int g = (blockIdx.x << 3) + (threadIdx.x >> 5);
    if (g >= E) return;
    const int lane = threadIdx.x & 31;
    const long src = (long)ei[g];
    const long dst = (long)ei[E + g];
    const int c = lane << 2;

    float kd[4], qs[4], vs[4];
    if constexpr (sizeof(T) == 4) {
        const float4 a = *reinterpret_cast<const float4*>(&kbuf[dst * 128 + c]);
        const float4 b = *reinterpret_cast<const float4*>(&qvbuf[src * 256 + c]);
        const float4 d = *reinterpret_cast<const float4*>(&qvbuf[src * 256 + 128 + c]);
        kd[0] = a.x; kd[1] = a.y; kd[2] = a.z; kd[3] = a.w;
        qs[0] = b.x; qs[1] = b.y; qs[2] = b.z; qs[3] = b.w;
        vs[0] = d.x; vs[1] = d.y; vs[2] = d.z; vs[3] = d.w;
    } else {
        const ushort4 a = *reinterpret_cast<const ushort4*>(&kbuf[dst * 128 + c]);
        const ushort4 b = *reinterpret_cast<const ushort4*>(&qvbuf[src * 256 + c]);
        const ushort4 d = *reinterpret_cast<const ushort4*>(&qvbuf[src * 256 + 128 + c]);
        kd[0] = bf2f(a.x); kd[1] = bf2f(a.y); kd[2] = bf2f(a.z); kd[3] = bf2f(a.w);
        qs[0] = bf2f(b.x); qs[1] = bf2f(b.y); qs[2] = bf2f(b.z); qs[3] = bf2f(b.w);
        vs[0] = bf2f(d.x); vs[1] = bf2f(d.y); vs[2] = bf2f(d.z); vs[3] = bf2f(d.w);
    }

    float* p = agg + dst * 128 + c;
#pragma unroll
    for (int j = 0; j < 4; ++j) {
        const float m = fmaxf(kd[j] + qs[j], 0.f) * vs[j];
        unsafeAtomicAdd(p + j, m);
    }
}

__global__ __launch_bounds__(64) void out_kernel(
    const float* agg, const float* __restrict__ bconv,
    const float* __restrict__ Wlin, const float* __restrict__ blin,
    float* out, int N)
{
    __shared__ float xt[32][DD];
    const int row0 = blockIdx.x * 32;
    const int t = threadIdx.x;

    for (int i = t; i < 32 * (DD / 4); i += 64) {
        const int r  = i >> 5;
        const int c4 = (i & 31) << 2;
        const int gr = row0 + r;
        float4 a = make_float4(0.f, 0.f, 0.f, 0.f);
        if (gr < N) a = *reinterpret_cast<const float4*>(&agg[(long)gr * DD + c4]);
        const float4 b = *reinterpret_cast<const float4*>(&bconv[c4]);
        float4 v;
        const float x0 = a.x + b.x; v.x = x0 >= 0.f ? x0 : 0.01f * x0;
        const float x1 = a.y + b.y; v.y = x1 >= 0.f ? x1 : 0.01f * x1;
        const float x2 = a.z + b.z; v.z = x2 >= 0.f ? x2 : 0.01f * x2;
        const float x3 = a.w + b.w; v.w = x3 >= 0.f ? x3 : 0.01f * x3;
        *reinterpret_cast<float4*>(&xt[r][c4]) = v;
    }
    __syncthreads();

    const int c0 = t;
    const int c1 = t + 64;
    float acc0[32], acc1[32];
#pragma unroll
    for (int r = 0; r < 32; ++r) { acc0[r] = 0.f; acc1[r] = 0.f; }

    for (int k4 = 0; k4 < DD; k4 += 4) {
        const float w00 = Wlin[(k4 + 0) * DD + c0];
        const float w01 = Wlin[(k4 + 1) * DD + c0];
        const float w02 = Wlin[(k4 + 2) * DD + c0];
        const float w03 = Wlin[(k4 + 3) * DD + c0];
        const float w10 = Wlin[(k4 + 0) * DD + c1];
        const float w11 = Wlin[(k4 + 1) * DD + c1];
        const float w12 = Wlin[(k4 + 2) * DD + c1];
        const float w13 = Wlin[(k4 + 3) * DD + c1];
#pragma unroll
        for (int r = 0; r < 32; ++r) {
            const float4 xv = *reinterpret_cast<const float4*>(&xt[r][k4]);
            acc0[r] = fmaf(xv.x, w00, fmaf(xv.y, w01, fmaf(xv.z, w02, fmaf(xv.w, w03, acc0[r]))));
            acc1[r] = fmaf(xv.x, w10, fmaf(xv.y, w11, fmaf(xv.z, w12, fmaf(xv.w, w13, acc1[r]))));
        }
    }

    const float bb0 = blin[c0];
    const float bb1 = blin[c1];
#pragma unroll
    for (int r = 0; r < 32; ++r) {
        const long gr = row0 + r;
        if (gr < N) {
            out[gr * DD + c0] = acc0[r] + bb0;
            out[gr * DD + c1] = acc1[r] + bb1;
        }
    }
}

// ---------------------------------------------------------------------------
extern "C" void kernel_launch(void* const* d_in, const int* in_sizes, int n_in,
                              void* d_out, int out_size, void* d_ws, size_t ws_size,
                              hipStream_t stream)
{
    const float* x     = (const float*)d_in[0];
    const int*   ei    = (const int*)d_in[1];      // int32 (harness converts int64 -> int32)
    const float* Wk    = (const float*)d_in[2];
    const float* bk    = (const float*)d_in[3];
    const float* Wq    = (const float*)d_in[4];
    const float* bq    = (const float*)d_in[5];
    const float* Wv    = (const float*)d_in[6];
    const float* bv    = (const float*)d_in[7];
    const float* Ws    = (const float*)d_in[8];
    const float* bconv = (const float*)d_in[9];
    const float* Wlin  = (const float*)d_in[10];
    const float* blin  = (const float*)d_in[11];

    const int N = in_sizes[0] / DD;
    const int E = in_sizes[1] / 2;

    float* aggf = (float*)d_out;                 // agg lives in d_out
    const int nblk    = (N + 31) / 32;
    const int mblk    = (N + 63) / 64;           // MFMA kernels: 64 rows/block
    const int eblk1   = (E + 255) / 256;
    const int nblk1   = (N + 255) / 256;
    const int gblk    = (N + 3) / 4;
    const int nchunks = (N + 1023) / 1024;       // <= 1024
    const int hblk    = (E + 511) / 512;         // hist tail blocks (512 thr)

    const int bsum_pad = (nchunks + 255) & ~255;

    // fast-path CSR layout: deg | off | cnt2 | bsum(bsum_pad) | done(256) | ssrc
    size_t csrF_ints = (size_t)3 * N + bsum_pad + 256 + E;
    csrF_ints = (csrF_ints + 3) & ~(size_t)3;
    const size_t csrF_bytes = csrF_ints * sizeof(int);

    // fallback CSR layout (round-5): deg | off | cursor | bsum | ssrc
    size_t csrO_ints = (size_t)3 * N + bsum_pad + E;
    csrO_ints = (csrO_ints + 3) & ~(size_t)3;
    const size_t csrO_bytes = csrO_ints * sizeof(int);

    const size_t projPK   = (size_t)N * (128 + 256) * sizeof(unsigned short); // k bf16 + qv packed bf16
    const size_t projF32  = (size_t)N * 384 * sizeof(float);
    const size_t projBF16 = (size_t)N * 384 * sizeof(unsigned short);
    const size_t wsplit   = (size_t)5 * 2048 * 8 * sizeof(unsigned short); // 160KB

    if (ws_size >= csrF_bytes + projPK + wsplit) {
        // ---- MFMA + packed-bf16-gather fast path (6 launches) ----
        int* deg  = (int*)d_ws;
        int* off  = deg + N;
        int* cnt2 = off + N;
        int* bsum = cnt2 + N;
        int* done = bsum + bsum_pad;
        int* ssrc = done + 256;
        unsigned short* kbuf = (unsigned short*)((char*)d_ws + csrF_bytes);
        unsigned short* qvpk = kbuf + (size_t)N * 128;
        unsigned short* whi  = qvpk + (size_t)N * 256;

        const int swblk = (N + 255) / 256;       // covers zeroing and frags
        split_w_kernel<<<swblk, 256, 0, stream>>>(Wk, Wq, Wv, Ws, Wlin, whi,
                                                  deg, cnt2, done, N);
        proj_mfma_kernel<<<mblk + hblk, 512, 0, stream>>>(x, whi, bk, bq, bv,
                                                          kbuf, qvpk, aggf,
                                                          ei, deg, mblk, E, N);
        scanAB_kernel<<<nchunks, 1024, 0, stream>>>(deg, off, bsum, done, N, nchunks);
        scatter2_kernel<<<eblk1, 256, 0, stream>>>(ei, off, bsum, cnt2, ssrc, E);
        gather_packed_kernel<<<gblk, 256, 0, stream>>>(off, bsum, deg, ssrc, kbuf, qvpk, aggf, N);
        out_mfma_kernel<<<mblk, 512, 0, stream>>>(aggf, bconv, whi, blin, (float*)d_out, N);
    } else if (ws_size >= csrO_bytes + projF32) {
        // ---- round-5 proven VALU path ----
        int* deg    = (int*)d_ws;
        int* off    = deg + N;
        int* cursor = off + N;
        int* bsum   = cursor + N;
        int* ssrc   = bsum + bsum_pad;
        float* kbuf  = (float*)((char*)d_ws + csrO_bytes);
        float* qvbuf = kbuf + (size_t)N * 128;

        proj_kernel<float><<<nblk, 256, 0, stream>>>(x, Wk, bk, Wq, bq, Wv, bv, Ws,
                                                     kbuf, qvbuf, aggf, N);
        zero_kernel<<<nblk1, 256, 0, stream>>>(deg, N);
        hist_kernel<<<eblk1, 256, 0, stream>>>(ei, deg, E);
        scanA_kernel<<<nchunks, 1024, 0, stream>>>(deg, off, bsum, N);
        scanB_kernel<<<1, 1024, 0, stream>>>(bsum, nchunks);
        scanC_kernel<<<nblk1, 256, 0, stream>>>(off, cursor, bsum, N);
        scatter_kernel<<<eblk1, 256, 0, stream>>>(ei, cursor, ssrc, E);
        gather_kernel<float><<<gblk, 256, 0, stream>>>(off, deg, ssrc, kbuf, qvbuf, aggf, N);
        out_kernel<<<nblk, 64, 0, stream>>>(aggf, bconv, Wlin, blin, (float*)d_out, N);
    } else if (ws_size >= csrO_bytes + projBF16) {
        int* deg    = (int*)d_ws;
        int* off    = deg + N;
        int* cursor = off + N;
        int* bsum   = cursor + N;
        int* ssrc   = bsum + bsum_pad;
        unsigned short* kbuf  = (unsigned short*)((char*)d_ws + csrO_bytes);
        unsigned short* qvbuf = kbuf + (size_t)N * 128;

        proj_kernel<unsigned short><<<nblk, 256, 0, stream>>>(x, Wk, bk, Wq, bq, Wv, bv, Ws,
                                                              kbuf, qvbuf, aggf, N);
        zero_kernel<<<nblk1, 256, 0, stream>>>(deg, N);
        hist_kernel<<<eblk1, 256, 0, stream>>>(ei, deg, E);
        scanA_kernel<<<nchunks, 1024, 0, stream>>>(deg, off, bsum, N);
        scanB_kernel<<<1, 1024, 0, stream>>>(bsum, nchunks);
        scanC_kernel<<<nblk1, 256, 0, stream>>>(off, cursor, bsum, N);
        scatter_kernel<<<eblk1, 256, 0, stream>>>(ei, cursor, ssrc, E);
        gather_kernel<unsigned short><<<gblk, 256, 0, stream>>>(off, deg, ssrc, kbuf, qvbuf, aggf, N);
        out_kernel<<<nblk, 64, 0, stream>>>(aggf, bconv, Wlin, blin, (float*)d_out, N);
    } else if (ws_size >= projBF16) {
        unsigned short* kbuf  = (unsigned short*)d_ws;
        unsigned short* qvbuf = kbuf + (size_t)N * 128;
        const int eblk8 = (E + 7) / 8;
        proj_kernel<unsigned short><<<nblk, 256, 0, stream>>>(x, Wk, bk, Wq, bq, Wv, bv, Ws,
                                                              kbuf, qvbuf, aggf, N);
        edge_kernel<unsigned short><<<eblk8, 256, 0, stream>>>(ei, kbuf, qvbuf, aggf, E);
        out_kernel<<<nblk, 64, 0, stream>>>(aggf, bconv, Wlin, blin, (float*)d_out, N);
    } else {
        hipMemsetAsync(d_out, 0, (size_t)out_size * sizeof(float), stream);
        return;
    }
}